// Round 13
// baseline (369.422 us; speedup 1.0000x reference)
//
#include <hip/hip_runtime.h>
#include <hip/hip_fp16.h>

#define T_LEN   262144
#define NV      20
#define NE      30
#define NH      40
#define CHUNK   256
#define WARM    64
#define SPC     (WARM + CHUNK)         // 320
#define NBLK    (T_LEN / CHUNK)        // 1024
#define SS      32                     // steps per super-step
#define NSS     (SPC / SS)             // 10
#define WUSS    (WARM / SS)            // 2
#define NTHR    128
#define NW4     1600                   // uint4 count: W_hh packs
#define NW4L    200                    // uint4 count: W_l packs

typedef unsigned u32x2  __attribute__((ext_vector_type(2)));

__device__ __forceinline__ float sig_(float x) {
    x = fminf(fmaxf(x, -30.f), 30.f);
    return __fdividef(1.f, 1.f + __expf(-x));
}
__device__ __forceinline__ float tanh_(float x) {
    x = fminf(fmaxf(x, -15.f), 15.f);
    float e = __expf(2.f * x);
    return __fdividef(e - 1.f, e + 1.f);
}
__device__ __forceinline__ unsigned pkf_(float a, float b) {
    unsigned lo = (unsigned)__half_as_ushort(__float2half(a));
    unsigned hi = (unsigned)__half_as_ushort(__float2half(b));
    return lo | (hi << 16);
}
__device__ __forceinline__ float lo16f_(unsigned u) {
    return __half2float(__ushort_as_half((unsigned short)(u & 0xffffu)));
}
__device__ __forceinline__ float hi16f_(unsigned u) {
    return __half2float(__ushort_as_half((unsigned short)(u >> 16)));
}
// Opaque 16B load: asm-produced values cannot be rematerialized.
__device__ __forceinline__ uint4 gload16_(const uint4* p) {
    uint4 r;
    asm volatile("global_load_dwordx4 %0, %1, off\n\ts_waitcnt vmcnt(0)"
                 : "=v"(r) : "v"(p) : "memory");
    return r;
}

#define D20(V) unsigned V##0,V##1,V##2,V##3,V##4,V##5,V##6,V##7,V##8,V##9, \
    V##10,V##11,V##12,V##13,V##14,V##15,V##16,V##17,V##18,V##19
#define A20(V, C0, C1, C2, C3, C4) do { \
    V##0 =C0.x; V##1 =C0.y; V##2 =C0.z; V##3 =C0.w; \
    V##4 =C1.x; V##5 =C1.y; V##6 =C1.z; V##7 =C1.w; \
    V##8 =C2.x; V##9 =C2.y; V##10=C2.z; V##11=C2.w; \
    V##12=C3.x; V##13=C3.y; V##14=C3.z; V##15=C3.w; \
    V##16=C4.x; V##17=C4.y; V##18=C4.z; V##19=C4.w; } while(0)
#define Z20(V) do { V##0=V##1=V##2=V##3=V##4=V##5=V##6=V##7=V##8=V##9=0u; \
    V##10=V##11=V##12=V##13=V##14=V##15=V##16=V##17=V##18=V##19=0u; } while(0)

#define H2(u) __builtin_bit_cast(__half2, (unsigned)(u))

// one readlane per h-PAIR feeding 4 packed-f16 FMA chains (v_pk_fma_f16 —
// guaranteed single VOP3P instr, unlike fdot2 which gfx950 legalizes into
// cvt/fma sequences: the 3x VALU tax R5-R12 all paid).
#define ACCP(M) do { \
    unsigned _hp = (unsigned)__builtin_amdgcn_readlane(hpair, 2*(M)); \
    __half2 _h2 = H2(_hp); \
    accI = __hfma2(_h2, H2(w##M),  accI); \
    accF = __hfma2(_h2, H2(wf##M), accF); \
    accG = __hfma2(_h2, H2(wg##M), accG); \
    accO = __hfma2(_h2, H2(wo##M), accO); \
} while(0)

// ---- prep kernel: pack weights as f16 pairs into d_ws ----
// wsW[((dir*4+g)*5+m4)*40+k] = uint4 of pairs m=4*m4+u of W_hh[g*40+k][.]
// wsW[1600 + (dir*5+m4)*20+v] = uint4 of pairs of W_l[v][.]
extern "C" __global__ void prep_kernel(const float* __restrict__ W_hh1,
                                       const float* __restrict__ W_hh2,
                                       const float* __restrict__ W_l1,
                                       const float* __restrict__ W_l2,
                                       uint4* __restrict__ ws)
{
    int tid = blockIdx.x * blockDim.x + threadIdx.x;
    for (int p = tid; p < NW4 + NW4L; p += blockDim.x * gridDim.x) {
        uint4 o;
        if (p < NW4) {
            int k = p % NH, r = p / NH;
            int m4 = r % 5;  r /= 5;
            int g  = r % 4;
            int dd = r / 4;
            const float* W = dd ? W_hh2 : W_hh1;
            const float* row = W + (g * NH + k) * NH + 8 * m4;
            o.x = pkf_(row[0], row[1]); o.y = pkf_(row[2], row[3]);
            o.z = pkf_(row[4], row[5]); o.w = pkf_(row[6], row[7]);
        } else {
            int q = p - NW4;
            int v = q % NV, r = q / NV;
            int m4 = r % 5;
            int dd = r / 5;
            const float* W = dd ? W_l2 : W_l1;
            const float* row = W + v * NH + 8 * m4;
            o.x = pkf_(row[0], row[1]); o.y = pkf_(row[2], row[3]);
            o.z = pkf_(row[4], row[5]); o.w = pkf_(row[6], row[7]);
        }
        ws[p] = o;
    }
}

// Blocks: 128 thr = 2 waves = 2 directions. Per wave: lanes 0-39 = LSTM units
// (80 packed-f16 W_hh words, asm-opaque loads), lanes 40-59 = logit riders
// (u = h_{s-1}·W_l on the same broadcasts). Triple-buffered u-ring, one
// barrier / 32 steps; wave 0 stores finished 32-row batches.
// 1024 blocks -> 4 blocks/CU (2 waves/SIMD) for stall overlap.
extern "C" __global__ void
__attribute__((amdgpu_waves_per_eu(1, 2), amdgpu_flat_work_group_size(NTHR, NTHR)))
bilstm_kernel(const int* __restrict__ tokens,
              const float* __restrict__ embed,
              const float* __restrict__ W_ih1,
              const float* __restrict__ b_ih1, const float* __restrict__ b_hh1,
              const float* __restrict__ W_ih2,
              const float* __restrict__ b_ih2, const float* __restrict__ b_hh2,
              const float* __restrict__ b_l1,  const float* __restrict__ b_l2,
              const uint4* __restrict__ wpk,
              float* __restrict__ out)
{
    __shared__ __align__(16) u32x2 xtab[2][NV][NH];        // f16-pair x-pre: (xi,xf),(xg,xo)
    __shared__ __align__(16) float uring[3][2][SS][NV];    // [buf][dir][slot][v]
    __shared__ __align__(16) float embS[NV * NE];
    __shared__ float biasS[NV];
    __shared__ int   tokS[2][SPC];

    const int tid  = threadIdx.x;
    const int wave = tid >> 6;          // == direction
    const int lane = tid & 63;
    const int dir  = wave;
    const int a    = blockIdx.x * CHUNK;

    // ---- stage embed + tokens + bias ----
    for (int p = tid; p < NV * NE; p += NTHR) embS[p] = embed[p];
    for (int p = tid; p < SPC; p += NTHR) {
        int t = a - WARM + p;
        if (t >= 0) {
            tokS[0][p] = tokens[t];
            tokS[1][p] = tokens[T_LEN - 1 - t];
        }
    }
    if (tid < NV) biasS[tid] = b_l1[tid] + b_l2[tid];
    __syncthreads();

    // ---- build x-pre table (f16 pairs): xtab[d][v][k] = {(xi,xf),(xg,xo)} ----
    for (int p = tid; p < 2 * NV * NH; p += NTHR) {
        int k = p % NH, q = p / NH;
        int v = q % NV, dd = q / NV;
        const float* Wih = dd ? W_ih2 : W_ih1;
        const float* bi  = dd ? b_ih2 : b_ih1;
        const float* bh  = dd ? b_hh2 : b_hh1;
        float x[4];
        #pragma unroll
        for (int g = 0; g < 4; ++g) {
            int j = g * NH + k;
            float acc = bi[j] + bh[j];
            #pragma unroll
            for (int e = 0; e < NE; ++e) acc += embS[v * NE + e] * Wih[j * NE + e];
            x[g] = acc;
        }
        u32x2 pk; pk.x = pkf_(x[0], x[1]); pk.y = pkf_(x[2], x[3]);
        xtab[dd][v][k] = pk;
    }

    // ---- per-lane weights: opaque 16B loads of pre-packed words ----
    const bool isUnit  = (lane < NH);
    const bool isLogit = (lane >= NH) && (lane < NH + NV);
    const int  kli     = isUnit ? lane : NH - 1;    // clamped xtab lane index

    D20(w); D20(wf); D20(wg); D20(wo);
    if (isUnit) {
        const uint4* b0 = wpk + ((dir * 4 + 0) * 5) * NH + lane;
        const uint4* b1 = wpk + ((dir * 4 + 1) * 5) * NH + lane;
        const uint4* b2 = wpk + ((dir * 4 + 2) * 5) * NH + lane;
        const uint4* b3 = wpk + ((dir * 4 + 3) * 5) * NH + lane;
        uint4 c0, c1, c2, c3, c4;
        c0=gload16_(b0); c1=gload16_(b0+NH); c2=gload16_(b0+2*NH); c3=gload16_(b0+3*NH); c4=gload16_(b0+4*NH);
        A20(w,  c0, c1, c2, c3, c4);
        c0=gload16_(b1); c1=gload16_(b1+NH); c2=gload16_(b1+2*NH); c3=gload16_(b1+3*NH); c4=gload16_(b1+4*NH);
        A20(wf, c0, c1, c2, c3, c4);
        c0=gload16_(b2); c1=gload16_(b2+NH); c2=gload16_(b2+2*NH); c3=gload16_(b2+3*NH); c4=gload16_(b2+4*NH);
        A20(wg, c0, c1, c2, c3, c4);
        c0=gload16_(b3); c1=gload16_(b3+NH); c2=gload16_(b3+2*NH); c3=gload16_(b3+3*NH); c4=gload16_(b3+4*NH);
        A20(wo, c0, c1, c2, c3, c4);
    } else {
        int vv = isLogit ? (lane - NH) : 0;
        const uint4* bl = wpk + NW4 + (dir * 5) * NV + vv;
        uint4 c0, c1, c2, c3, c4;
        c0=gload16_(bl); c1=gload16_(bl+NV); c2=gload16_(bl+2*NV); c3=gload16_(bl+3*NV); c4=gload16_(bl+4*NV);
        A20(w, c0, c1, c2, c3, c4);
        Z20(wf); Z20(wg); Z20(wo);
    }
    __syncthreads();   // xtab + tokS ready

    // ---- init + first x prefetch ----
    const int cell_ss0 = (a < WARM) ? WUSS : 0;   // block 0 starts exactly at s=WARM
    int   hb = 0;                                  // f16 bits of own h (lanes 0-39)
    float c  = 0.f;
    u32x2 xv;
    {
        int tk = tokS[dir][cell_ss0 * SS];
        xv = xtab[dir][tk][kli];
    }

    // ---- main loop (super-step NSS = 1 extra iteration to finish last batch) ----
    #pragma unroll 1
    for (int ss = cell_ss0; ss <= NSS; ++ss) {
        const int sbase = ss * SS;
        const int nsl   = (ss < NSS) ? SS : 1;
        #pragma unroll 1
        for (int sl = 0; sl < nsl; ++sl) {
            const int s = sbase + sl;
            // pack h pairs via DPP quad_perm [1,0,3,2] (xor lane bit 0)
            unsigned nb = (unsigned)__builtin_amdgcn_mov_dpp((int)hb, 0xB1, 0xF, 0xF, true);
            unsigned hpair = ((unsigned)hb & 0xffffu) | (nb << 16);
            __half2 accI = H2(0u), accF = H2(0u), accG = H2(0u), accO = H2(0u);
            ACCP(0);  ACCP(1);  ACCP(2);  ACCP(3);  ACCP(4);
            ACCP(5);  ACCP(6);  ACCP(7);  ACCP(8);  ACCP(9);
            ACCP(10); ACCP(11); ACCP(12); ACCP(13); ACCP(14);
            ACCP(15); ACCP(16); ACCP(17); ACCP(18); ACCP(19);
            float ai = __low2float(accI) + __high2float(accI);
            float af = __low2float(accF) + __high2float(accF);
            float ag = __low2float(accG) + __high2float(accG);
            float ao = __low2float(accO) + __high2float(accO);
            if (isUnit) {
                ai += lo16f_(xv.x); af += hi16f_(xv.x);
                ag += lo16f_(xv.y); ao += hi16f_(xv.y);
            }
            const float uval = ai;                  // logit lanes: u = h_{s-1}·W_l
            if (isLogit && s >= 1) {                // belongs to output step s-1
                int us = s - 1;
                uring[(us >> 5) % 3][dir][us & 31][lane - NH] = uval;
            }
            int sn = (s + 1 < SPC) ? s + 1 : SPC - 1;
            int tk = tokS[dir][sn];
            xv = xtab[dir][tk][kli];                // prefetch next x
            float I = sig_(ai), F = sig_(af), G = tanh_(ag), O = sig_(ao);
            c = fmaf(F, c, I * G);
            float hh = O * tanh_(c);
            hb = (int)__half_as_ushort(__float2half(hh));
        }
        __syncthreads();
        if (wave == 0 && ss > WUSS) {               // store finished batch B = ss-1
            const int B   = ss - 1;
            const int buf = B % 3;
            const size_t rbase = (size_t)(a + B * SS - WARM) * NV;
            #pragma unroll
            for (int i = 0; i < (SS * NV) / 64; ++i) {   // 10
                int e = i * 64 + lane;
                int row = e / NV, v = e - row * NV;
                float sum = uring[buf][0][row][v] + uring[buf][1][row][v] + biasS[v];
                out[rbase + e] = sum;
            }
        }
    }
}

extern "C" void kernel_launch(void* const* d_in, const int* in_sizes, int n_in,
                              void* d_out, int out_size, void* d_ws, size_t ws_size,
                              hipStream_t stream)
{
    const int*   tokens = (const int*)  d_in[0];
    const float* embed  = (const float*)d_in[1];
    const float* W_ih1  = (const float*)d_in[2];
    const float* W_hh1  = (const float*)d_in[3];
    const float* b_ih1  = (const float*)d_in[4];
    const float* b_hh1  = (const float*)d_in[5];
    const float* W_ih2  = (const float*)d_in[6];
    const float* W_hh2  = (const float*)d_in[7];
    const float* b_ih2  = (const float*)d_in[8];
    const float* b_hh2  = (const float*)d_in[9];
    const float* W_l1   = (const float*)d_in[10];
    const float* b_l1   = (const float*)d_in[11];
    const float* W_l2   = (const float*)d_in[12];
    const float* b_l2   = (const float*)d_in[13];
    float* outp = (float*)d_out;
    uint4* wpk  = (uint4*)d_ws;

    hipLaunchKernelGGL(prep_kernel, dim3(8), dim3(256), 0, stream,
                       W_hh1, W_hh2, W_l1, W_l2, wpk);
    hipLaunchKernelGGL(bilstm_kernel, dim3(NBLK), dim3(NTHR), 0, stream,
                       tokens, embed, W_ih1, b_ih1, b_hh1,
                       W_ih2, b_ih2, b_hh2, b_l1, b_l2, wpk, outp);
}